// Round 4
// baseline (83.668 us; speedup 1.0000x reference)
//
#include <hip/hip_runtime.h>

// out[b,u] = prod_i ( x[b,i]*w[i,u] + (1 - w[i,u]) )
// B=2048, IN_DIM=256, UNITS=512
//
// Round 4: 2-D register tiling to kill the x-broadcast bottleneck.
// Each thread owns a 4b x 4u tile: per i it reads 4 x + 4 w values
// (2 ds_read_b128) and does 16 fma + 16 mul -> LDS instrs amortized 18:1
// by VALU. Block 16x16 threads -> 64x64 output tile; grid 8x32 = 256
// blocks = 1 per CU. x staged TRANSPOSED in LDS (xs[i][b], lane->b map:
// transpose writes land 2 lanes/bank = free); w staged natural (coalesced
// global float4, b128 LDS writes, bank-uniform). Compute reads: x b128
// 16-way broadcast (free), w b128 2-way (free).

#define B_DIM   2048
#define IN_DIM  256
#define UNITS   512
#define BT      64      // block tile in b
#define UT      64      // block tile in u
#define KI      64      // i-chunk staged per round
#define BLOCK   256

__global__ __launch_bounds__(BLOCK) void prodw_kernel(
    const float* __restrict__ x,   // [B, IN_DIM]
    const float* __restrict__ w,   // [IN_DIM, UNITS]
    float* __restrict__ out)       // [B, UNITS]
{
    __shared__ __align__(16) float xs[KI][BT];  // transposed: xs[i][b]
    __shared__ __align__(16) float ws[KI][UT];  // natural:    ws[i][u]

    const int tid  = threadIdx.x;
    const int tx   = tid & 15;          // u-quad selector
    const int ty   = tid >> 4;          // b-quad selector
    const int ublk = blockIdx.x * UT;
    const int bblk = blockIdx.y * BT;

    float acc[4][4];
#pragma unroll
    for (int a = 0; a < 4; ++a)
#pragma unroll
        for (int b = 0; b < 4; ++b) acc[a][b] = 1.0f;

    const int bl   = tid & 63;          // x staging: lane -> b row (distinct per wave)
    const int half = tid >> 6;          // x staging: wave -> i-subrange

    for (int ic = 0; ic < IN_DIM / KI; ++ic) {
        const int ibase = ic * KI;

        // ---- stage x chunk, transposed ----
        // thread covers global row (bblk+bl), i in [ibase + half*16, +16).
        // LDS writes xs[i][bl]: bank = bl%32, 2 lanes/bank -> conflict-free.
        {
            const float* __restrict__ xr =
                x + (size_t)(bblk + bl) * IN_DIM + ibase + half * 16;
#pragma unroll
            for (int r = 0; r < 4; ++r) {
                const float4 f = *(const float4*)(xr + r * 4);
                const int i0 = half * 16 + r * 4;
                xs[i0 + 0][bl] = f.x;
                xs[i0 + 1][bl] = f.y;
                xs[i0 + 2][bl] = f.z;
                xs[i0 + 3][bl] = f.w;
            }
        }
        // ---- stage w chunk, natural layout (coalesced float4) ----
        {
#pragma unroll
            for (int r = 0; r < 4; ++r) {
                const int idx = r * BLOCK + tid;
                const int il  = idx >> 4;          // 0..63
                const int u4  = (idx & 15) * 4;    // 0..60
                const float4 f = *(const float4*)
                    (w + (size_t)(ibase + il) * UNITS + ublk + u4);
                *(float4*)&ws[il][u4] = f;
            }
        }
        __syncthreads();

        // ---- compute over this chunk ----
#pragma unroll 8
        for (int il = 0; il < KI; ++il) {
            const float4 xq = *(const float4*)&xs[il][ty * 4];  // 4 b values
            const float4 wq = *(const float4*)&ws[il][tx * 4];  // 4 u values
            const float xv[4] = {xq.x, xq.y, xq.z, xq.w};
            const float wv[4] = {wq.x, wq.y, wq.z, wq.w};
            const float cv[4] = {1.0f - wq.x, 1.0f - wq.y,
                                 1.0f - wq.z, 1.0f - wq.w};
#pragma unroll
            for (int jb = 0; jb < 4; ++jb)
#pragma unroll
                for (int ju = 0; ju < 4; ++ju)
                    acc[jb][ju] *= fmaf(xv[jb], wv[ju], cv[ju]);
        }
        __syncthreads();
    }

    // ---- store: 4 coalesced float4 rows ----
#pragma unroll
    for (int jb = 0; jb < 4; ++jb) {
        const float4 o = {acc[jb][0], acc[jb][1], acc[jb][2], acc[jb][3]};
        *(float4*)(out + (size_t)(bblk + ty * 4 + jb) * UNITS + ublk + tx * 4) = o;
    }
}

extern "C" void kernel_launch(void* const* d_in, const int* in_sizes, int n_in,
                              void* d_out, int out_size, void* d_ws, size_t ws_size,
                              hipStream_t stream) {
    const float* x = (const float*)d_in[0];        // 2048*256
    const float* w = (const float*)d_in[1];        // 256*512
    float* out     = (float*)d_out;                // 2048*512

    dim3 grid(UNITS / UT, B_DIM / BT);             // (8, 32) = 256 blocks
    dim3 block(BLOCK);
    prodw_kernel<<<grid, block, 0, stream>>>(x, w, out);
}

// Round 5
// 80.715 us; speedup vs baseline: 1.0366x; 1.0366x over previous
//
#include <hip/hip_runtime.h>

// out[b,u] = prod_i ( x[b,i]*w[i,u] + (1 - w[i,u]) )
// B=2048, IN_DIM=256, UNITS=512
//
// Round 5: 8b x 4u thread tile (3 ds_read_b128 serve 32 cells -> LDS pipe
// balanced with VALU floor) + split-i x8 for occupancy (1024 blocks = 4
// blocks/CU = 4 waves/SIMD; R4's fatal flaw was 1 wave/SIMD). Each block
// computes a partial product over 32 i values into d_ws; a combine kernel
// multiplies the 8 partials. x staged transposed (lane<->b: 2 lanes/bank
// writes = free, broadcast reads = free); w rows padded to 68 floats
// (16B-aligned b128, 2-way compute reads = free).

#define B_DIM   2048
#define IN_DIM  256
#define UNITS   512
#define BT      128     // block tile in b
#define UT      64      // block tile in u
#define KI      32      // i-range per block (split-i)
#define NS      8       // i splits
#define BLOCK   256
#define WSPAD   68      // padded row stride for ws (floats)

__global__ __launch_bounds__(BLOCK, 4) void prodw_main(
    const float* __restrict__ x,     // [B, IN_DIM]
    const float* __restrict__ w,     // [IN_DIM, UNITS]
    float* __restrict__ part)        // [NS, B, UNITS] partial products
{
    __shared__ __align__(16) float xs[KI * BT];     // transposed: xs[i*BT + b], 16 KB
    __shared__ __align__(16) float ws[KI * WSPAD];  // natural, padded, 8.7 KB

    const int tid   = threadIdx.x;
    const int ublk  = blockIdx.x * UT;
    const int bblk  = blockIdx.y * BT;
    const int sbase = blockIdx.z * KI;

    // ---- stage x chunk, transposed: 128 b x 32 i ----
    // b-major lane map: LDS write bank = b%32 -> 2 lanes/bank (free).
#pragma unroll
    for (int r = 0; r < 4; ++r) {
        const int idx = r * BLOCK + tid;
        const int b   = idx & (BT - 1);
        const int i4  = (idx >> 7) << 2;            // 0,4,...,28
        const float4 f = *(const float4*)(x + (size_t)(bblk + b) * IN_DIM + sbase + i4);
        xs[(i4 + 0) * BT + b] = f.x;
        xs[(i4 + 1) * BT + b] = f.y;
        xs[(i4 + 2) * BT + b] = f.z;
        xs[(i4 + 3) * BT + b] = f.w;
    }
    // ---- stage w chunk, natural layout, padded rows: 32 i x 64 u ----
#pragma unroll
    for (int r = 0; r < 2; ++r) {
        const int idx = r * BLOCK + tid;
        const int il  = idx >> 4;                   // 0..31
        const int u4  = (idx & 15) * 4;             // 0..60
        const float4 f = *(const float4*)(w + (size_t)(sbase + il) * UNITS + ublk + u4);
        *(float4*)&ws[il * WSPAD + u4] = f;         // 16B-aligned (WSPAD*4 % 16 == 0)
    }
    __syncthreads();

    const int tx = tid & 15;    // u quad: cols ublk + tx*4 .. +3
    const int ty = tid >> 4;    // b octet: rows bblk + ty*8 .. +7

    float acc[8][4];
#pragma unroll
    for (int jb = 0; jb < 8; ++jb)
#pragma unroll
        for (int ju = 0; ju < 4; ++ju) acc[jb][ju] = 1.0f;

#pragma unroll 4
    for (int il = 0; il < KI; ++il) {
        const float4 wq = *(const float4*)&ws[il * WSPAD + tx * 4];  // 2-way, free
        const float4 xa = *(const float4*)&xs[il * BT + ty * 8];     // broadcast
        const float4 xb = *(const float4*)&xs[il * BT + ty * 8 + 4]; // broadcast

        const float wv[4] = {wq.x, wq.y, wq.z, wq.w};
        const float cv[4] = {1.0f - wq.x, 1.0f - wq.y, 1.0f - wq.z, 1.0f - wq.w};
        const float xv[8] = {xa.x, xa.y, xa.z, xa.w, xb.x, xb.y, xb.z, xb.w};

#pragma unroll
        for (int jb = 0; jb < 8; ++jb)
#pragma unroll
            for (int ju = 0; ju < 4; ++ju)
                acc[jb][ju] *= fmaf(xv[jb], wv[ju], cv[ju]);   // 32 fma + 32 mul / i
    }

    // ---- write partial tile (coalesced float4) ----
    float* __restrict__ po = part + (size_t)blockIdx.z * (B_DIM * UNITS);
#pragma unroll
    for (int jb = 0; jb < 8; ++jb) {
        const float4 o = {acc[jb][0], acc[jb][1], acc[jb][2], acc[jb][3]};
        *(float4*)(po + (size_t)(bblk + ty * 8 + jb) * UNITS + ublk + tx * 4) = o;
    }
}

__global__ __launch_bounds__(BLOCK) void prodw_combine(
    const float* __restrict__ part,  // [NS, B*UNITS]
    float* __restrict__ out)         // [B*UNITS]
{
    const size_t off = ((size_t)blockIdx.x * BLOCK + threadIdx.x) * 4;
    float4 p = *(const float4*)(part + off);
#pragma unroll
    for (int s = 1; s < NS; ++s) {
        const float4 q = *(const float4*)(part + (size_t)s * (B_DIM * UNITS) + off);
        p.x *= q.x; p.y *= q.y; p.z *= q.z; p.w *= q.w;
    }
    *(float4*)(out + off) = p;
}

extern "C" void kernel_launch(void* const* d_in, const int* in_sizes, int n_in,
                              void* d_out, int out_size, void* d_ws, size_t ws_size,
                              hipStream_t stream) {
    const float* x = (const float*)d_in[0];        // 2048*256
    const float* w = (const float*)d_in[1];        // 256*512
    float* out     = (float*)d_out;                // 2048*512
    float* part    = (float*)d_ws;                 // NS * 4 MB = 32 MB scratch

    dim3 gmain(UNITS / UT, B_DIM / BT, NS);        // (8, 16, 8) = 1024 blocks
    prodw_main<<<gmain, BLOCK, 0, stream>>>(x, w, part);

    const int n4 = B_DIM * UNITS / 4;              // 262144 float4s
    prodw_combine<<<n4 / BLOCK, BLOCK, 0, stream>>>(part, out);
}

// Round 6
// 73.633 us; speedup vs baseline: 1.1363x; 1.0962x over previous
//
#include <hip/hip_runtime.h>

// out[b,u] = prod_i ( x[b,i]*w[i,u] + (1 - w[i,u]) )
// B=2048, IN_DIM=256, UNITS=512
//
// Round 6: intra-block i-split (one dispatch, no d_ws).
// Block = 256 threads = 8 i-slices x 32 cell-threads. Each thread: 8b x 8u
// tile over 32 i -> per i, 4 ds_read_b128 serve 64 cells (LDS pipe 12.3k
// cyc/CU < VALU 16.4k floor). Grid (8,64)=512 blocks = 2/CU = 8 waves/CU.
// Staging per chunk: 64 rows = 8 i per slice; x transposed (2 lanes/bank
// writes, broadcast reads); w rows XOR-swizzled by slice parity (cols ^4)
// so wave halves hit disjoint banks (worst 2-way = free). After the K loop,
// binary-tree combine of the 8 slice partials through reused LDS (3 rounds),
// slice 0 stores. Packed v2f math (v_pk_fma/mul) along u.

typedef float v2f __attribute__((ext_vector_type(2)));

#define B_DIM   2048
#define IN_DIM  256
#define UNITS   512
#define BT      32      // block tile b
#define UT      64      // block tile u
#define BLOCK   256
#define NSL     8       // i-slices per block
#define KIS     32      // i per slice
#define CHUNK   8       // i per slice per staging chunk
#define NCH     4       // chunks (KIS/CHUNK)
#define PSTR    68      // combine plane: per-thread float stride (4-way max)
#define PLANE   (32*PSTR)  // 2176 floats per plane

__global__ __launch_bounds__(BLOCK) void prodw_kernel(
    const float* __restrict__ x,   // [B, IN_DIM]
    const float* __restrict__ w,   // [IN_DIM, UNITS]
    float* __restrict__ out)       // [B, UNITS]
{
    // 34.8 KB, dual-purpose: staging (xs 2048 + ws 4096 floats) / combine (4 planes)
    __shared__ __align__(16) float lds[4 * PLANE];
    float* __restrict__ xs  = lds;          // [64][32]  row = s*8+ii, col = b
    float* __restrict__ wsb = lds + 2048;   // [64][64]  row = s*8+ii, col = u^swz

    const int tid = threadIdx.x;
    const int s   = tid >> 5;        // i-slice 0..7
    const int t   = tid & 31;        // cell-thread 0..31
    const int tb  = t >> 3;          // b-octet 0..3
    const int tu  = t & 7;           // u-octet 0..7
    const int ublk = blockIdx.x * UT;
    const int bblk = blockIdx.y * BT;

    __align__(16) float af[64];      // acc tile [jb][ju], viewed as v2f for pk math
    v2f* __restrict__ acc = (v2f*)af;          // acc[jb*4 + q] = u pair (2q,2q+1)
#pragma unroll
    for (int k = 0; k < 32; ++k) acc[k] = (v2f){1.0f, 1.0f};

    const int swz = (s & 1) << 2;    // compute-side w col swizzle

    for (int c = 0; c < NCH; ++c) {
        __syncthreads();             // prior chunk's reads done before overwrite

        // ---- stage x chunk, transposed: rows (s*8+li), cols b ----
        // write bank = b%32, 2 lanes/bank -> free
#pragma unroll
        for (int r = 0; r < 2; ++r) {
            const int idx  = r * BLOCK + tid;
            const int b    = idx & 31;
            const int srow = idx >> 5;        // 0..15
            const int ss   = srow >> 1;
            const int h    = srow & 1;
            const float4 f = *(const float4*)
                (x + (size_t)(bblk + b) * IN_DIM + ss * KIS + c * CHUNK + h * 4);
            const int row = ss * 8 + h * 4;
            xs[(row + 0) * 32 + b] = f.x;
            xs[(row + 1) * 32 + b] = f.y;
            xs[(row + 2) * 32 + b] = f.z;
            xs[(row + 3) * 32 + b] = f.w;
        }
        // ---- stage w chunk: rows (s*8+ii), cols u ^ slice-parity swizzle ----
#pragma unroll
        for (int r = 0; r < 4; ++r) {
            const int idx = r * BLOCK + tid;
            const int row = idx >> 4;         // 0..63
            const int u4  = (idx & 15) * 4;
            const int ss  = row >> 3;
            const int ii  = row & 7;
            const int xr  = (ss & 1) << 2;
            const float4 f = *(const float4*)
                (w + (size_t)(ss * KIS + c * CHUNK + ii) * UNITS + ublk + u4);
            *(float4*)&wsb[row * 64 + (u4 ^ xr)] = f;
        }
        __syncthreads();

        // ---- compute this chunk's 8 i for slice s ----
#pragma unroll
        for (int ii = 0; ii < CHUNK; ++ii) {
            const int row = s * 8 + ii;
            const float4 xa = *(const float4*)&xs[row * 32 + tb * 8];      // bcast
            const float4 xb = *(const float4*)&xs[row * 32 + tb * 8 + 4];  // bcast
            const float4 w0 = *(const float4*)&wsb[row * 64 + ((tu * 8) ^ swz)];
            const float4 w1 = *(const float4*)&wsb[row * 64 + ((tu * 8 + 4) ^ swz)];

            v2f wv[4] = {{w0.x, w0.y}, {w0.z, w0.w}, {w1.x, w1.y}, {w1.z, w1.w}};
            v2f cv[4];
#pragma unroll
            for (int q = 0; q < 4; ++q) cv[q] = (v2f){1.0f, 1.0f} - wv[q];
            const float xv[8] = {xa.x, xa.y, xa.z, xa.w, xb.x, xb.y, xb.z, xb.w};

#pragma unroll
            for (int jb = 0; jb < 8; ++jb) {
                const v2f xbv = {xv[jb], xv[jb]};
#pragma unroll
                for (int q = 0; q < 4; ++q)
                    acc[jb * 4 + q] *= __builtin_elementwise_fma(xbv, wv[q], cv[q]);
            }
        }
    }

    // ---- binary-tree combine of 8 slice partials through LDS ----
#pragma unroll
    for (int half = NSL / 2; half >= 1; half >>= 1) {
        __syncthreads();
        if (s >= half && s < 2 * half) {
            float* __restrict__ pl = lds + (size_t)(s - half) * PLANE + t * PSTR;
#pragma unroll
            for (int k = 0; k < 16; ++k)
                *(float4*)&pl[k * 4] = ((const float4*)af)[k];
        }
        __syncthreads();
        if (s < half) {
            const float* __restrict__ pl = lds + (size_t)s * PLANE + t * PSTR;
#pragma unroll
            for (int k = 0; k < 16; ++k) {
                const float4 q = *(const float4*)&pl[k * 4];
                float4* a4 = &((float4*)af)[k];
                a4->x *= q.x; a4->y *= q.y; a4->z *= q.z; a4->w *= q.w;
            }
        }
    }

    // ---- slice 0 stores the 32x64 block tile ----
    if (s == 0) {
#pragma unroll
        for (int jb = 0; jb < 8; ++jb) {
            float* __restrict__ po =
                out + (size_t)(bblk + tb * 8 + jb) * UNITS + ublk + tu * 8;
            *(float4*)(po)     = *(const float4*)&af[jb * 8];
            *(float4*)(po + 4) = *(const float4*)&af[jb * 8 + 4];
        }
    }
}

extern "C" void kernel_launch(void* const* d_in, const int* in_sizes, int n_in,
                              void* d_out, int out_size, void* d_ws, size_t ws_size,
                              hipStream_t stream) {
    const float* x = (const float*)d_in[0];        // 2048*256
    const float* w = (const float*)d_in[1];        // 256*512
    float* out     = (float*)d_out;                // 2048*512

    dim3 grid(UNITS / UT, B_DIM / BT);             // (8, 64) = 512 blocks
    prodw_kernel<<<grid, BLOCK, 0, stream>>>(x, w, out);
}